// Round 1
// baseline (160.864 us; speedup 1.0000x reference)
//
#include <hip/hip_runtime.h>
#include <math.h>

#define NQ 12
#define DIM 4096
#define NLAYER 4
#define NTHREADS 512
#define EPT (DIM / NTHREADS)  // 8 complex elems per thread

__device__ inline float block_reduce_sum(float v, float* red) {
    const int tid = threadIdx.x;
#pragma unroll
    for (int off = 32; off > 0; off >>= 1)
        v += __shfl_down(v, off, 64);
    const int wave = tid >> 6;
    if ((tid & 63) == 0) red[wave] = v;
    __syncthreads();
    if (tid == 0) {
        float s = 0.f;
#pragma unroll
        for (int i = 0; i < NTHREADS / 64; ++i) s += red[i];
        red[0] = s;
    }
    __syncthreads();
    float r = red[0];
    __syncthreads();  // protect red before any reuse
    return r;
}

__global__ __launch_bounds__(NTHREADS, 4) void qsim_kernel(
    const float* __restrict__ x, const float* __restrict__ w,
    float* __restrict__ out) {
    __shared__ float2 st[DIM];              // 32 KB statevector
    __shared__ float2 gmat[NLAYER * NQ * 4];  // 48 gates x 4 complex entries
    __shared__ float red[NTHREADS / 64];

    const int tid = threadIdx.x;
    const long b = blockIdx.x;
    const float* xrow = x + b * (long)DIM;

    // --- gate matrices (one thread each for the 48 gates) ---
    if (tid < NLAYER * NQ) {
        const float* wp = w + tid * 3;
        float phi = wp[0], th = wp[1], om = wp[2];
        float s, c, sa, ca, sb, cb;
        sincosf(0.5f * th, &s, &c);
        sincosf(0.5f * (phi + om), &sa, &ca);
        sincosf(0.5f * (phi - om), &sb, &cb);
        float2* g = &gmat[tid * 4];
        g[0] = make_float2(ca * c, -sa * c);   // U00 = e^{-i(phi+om)/2} cos
        g[1] = make_float2(-cb * s, -sb * s);  // U01 = -e^{+i(phi-om)/2} sin
        g[2] = make_float2(cb * s, -sb * s);   // U10 = e^{-i(phi-om)/2} sin
        g[3] = make_float2(ca * c, sa * c);    // U11 = e^{+i(phi+om)/2} cos
    }

    // --- load x row, L2 norm, amplitude-encode into LDS ---
    float xv[EPT];
    float ss = 0.f;
#pragma unroll
    for (int i = 0; i < EPT; ++i) {
        float v = xrow[tid + i * NTHREADS];
        xv[i] = v;
        ss += v * v;
    }
    float nrm = sqrtf(block_reduce_sum(ss, red));
    bool ok = nrm > 1e-10f;
    float inv = ok ? (1.0f / nrm) : 0.f;
#pragma unroll
    for (int i = 0; i < EPT; ++i) {
        float a = ok ? xv[i] * inv : 0.015625f;  // 1/sqrt(4096)
        st[tid + i * NTHREADS] = make_float2(a, 0.f);
    }

    // --- circuit: 4 layers of (12 Rot gates + CNOT-cascade permutation) ---
    for (int layer = 0; layer < NLAYER; ++layer) {
        for (int q = 0; q < NQ; ++q) {
            __syncthreads();
            const float2* g = &gmat[(layer * NQ + q) * 4];
            const float2 u00 = g[0], u01 = g[1], u10 = g[2], u11 = g[3];
            const int p = (NQ - 1) - q;  // bit position of qubit q (q0 = MSB)
            const int str = 1 << p;
#pragma unroll
            for (int it = 0; it < DIM / 2 / NTHREADS; ++it) {
                int t = tid + it * NTHREADS;  // pair index 0..2047
                int i0 = ((t >> p) << (p + 1)) | (t & (str - 1));
                int i1 = i0 + str;
                float2 s0 = st[i0], s1 = st[i1];
                float2 n0, n1;
                n0.x = u00.x * s0.x - u00.y * s0.y + u01.x * s1.x - u01.y * s1.y;
                n0.y = u00.x * s0.y + u00.y * s0.x + u01.x * s1.y + u01.y * s1.x;
                n1.x = u10.x * s0.x - u10.y * s0.y + u11.x * s1.x - u11.y * s1.y;
                n1.y = u10.x * s0.y + u10.y * s0.x + u11.x * s1.y + u11.y * s1.x;
                st[i0] = n0;
                st[i1] = n1;
            }
        }
        // CNOT cascade == fixed permutation: src bit_j = XOR(y bits MSB..j)
        __syncthreads();
        float2 vals[EPT];
#pragma unroll
        for (int i = 0; i < EPT; ++i) {
            int y = tid + i * NTHREADS;
            int z = y;
            z ^= z >> 1;
            z ^= z >> 2;
            z ^= z >> 4;
            z ^= z >> 8;
            vals[i] = st[z & (DIM - 1)];
        }
        __syncthreads();
#pragma unroll
        for (int i = 0; i < EPT; ++i) st[tid + i * NTHREADS] = vals[i];
    }

    // --- probabilities + renormalize + store ---
    __syncthreads();
    float pr[EPT];
    float psum = 0.f;
#pragma unroll
    for (int i = 0; i < EPT; ++i) {
        float2 v = st[tid + i * NTHREADS];
        float pp = v.x * v.x + v.y * v.y;
        pr[i] = pp;
        psum += pp;
    }
    float tot = block_reduce_sum(psum, red);
    bool okp = tot > 1e-10f;
    float invt = okp ? (1.0f / tot) : 0.f;
    float* orow = out + b * (long)DIM;
#pragma unroll
    for (int i = 0; i < EPT; ++i) {
        orow[tid + i * NTHREADS] = okp ? pr[i] * invt : (1.0f / DIM);
    }
}

extern "C" void kernel_launch(void* const* d_in, const int* in_sizes, int n_in,
                              void* d_out, int out_size, void* d_ws, size_t ws_size,
                              hipStream_t stream) {
    const float* x = (const float*)d_in[0];
    const float* w = (const float*)d_in[1];
    float* out = (float*)d_out;
    const int B = in_sizes[0] / DIM;
    qsim_kernel<<<B, NTHREADS, 0, stream>>>(x, w, out);
}